// Round 8
// baseline (497.982 us; speedup 1.0000x reference)
//
#include <hip/hip_runtime.h>
#include <stdint.h>

typedef __bf16 bf16x8 __attribute__((ext_vector_type(8)));
typedef float  f32x4  __attribute__((ext_vector_type(4)));
typedef unsigned short u16x4 __attribute__((ext_vector_type(4)));

// ---- geometry ----
// rows kernel (R7, proven): 64 rows/block, 512 thr; gather + PE MLP + x2 cvt
//   -> xbf [262144][288] bf16 pre-swizzled (XOR bits 4-5 by ((row>>1)&3)<<4).
// gemm kernel: 64 rows/block, 512 thr (8 waves), LDS 54272 -> 3 blocks/CU
//   (24 waves). GEMM1 in 4 N-passes of 128 cols (acc[2][2]); after each pass
//   its h-quarter goes to a 17 KB LDS region and GEMM2's matching K-quarter
//   runs (acc2[2][3] accumulates across quarters). Registers ~70 -> 6 w/SIMD.
#define XROW_B  576     // x row stride bytes (288 bf16)
#define HQROW_B 272     // h-quarter row stride bytes (128 bf16 + pad)
#define HQ_OFF  36864
#define LDS_SZ  54272

#define RLDS_W  36864   // rows kernel: W1/b1 f32[540] after x tile
#define RLDS_SZ 39040

// workspace offsets (bytes)
#define WS_FC1T   0         // bf16 [512][288]
#define WS_FC2T   294912    // bf16 [192][512]
#define WS_BIAS   491520    // f32  [512]
#define WS_XBF    524288    // bf16 [262144][288] pre-swizzled

__device__ __forceinline__ unsigned short f2bf(float f) {
  union { float f; unsigned u; } c; c.f = f;
  unsigned u = c.u;
  u += 0x7FFFu + ((u >> 16) & 1u);   // RTNE
  return (unsigned short)(u >> 16);
}

__device__ __forceinline__ unsigned cvtpk(float lo, float hi) {
  unsigned r;
  asm("v_cvt_pk_bf16_f32 %0, %1, %2" : "=v"(r) : "v"(lo), "v"(hi));
  return r;
}

__device__ __forceinline__ void g2l16(const void* g, void* l) {
  __builtin_amdgcn_global_load_lds(
      (const __attribute__((address_space(1))) void*)g,
      (__attribute__((address_space(3))) void*)l, 16, 0, 0);
}

// ---------------- prep: fold W2 into fc1_w, transpose + bf16 ----------------
__global__ void POLAR_prep_fc1(const float* __restrict__ W2,
                               const float* __restrict__ fc1_w,
                               const float* __restrict__ fc1_b,
                               const float* __restrict__ b2,
                               unsigned short* __restrict__ fc1t,
                               float* __restrict__ bias_eff) {
  int n = blockIdx.x;      // 0..511
  int k = threadIdx.x;     // 0..287
  float v = 0.f;
  if (k < 108) {
    for (int f = 0; f < 108; ++f) v += W2[k*108 + f] * fc1_w[f*512 + n];
  } else if (k < 280) {
    v = fc1_w[k*512 + n];
  }
  fc1t[n*288 + k] = f2bf(v);
  if (k == 0) {
    float bb = fc1_b[n];
    for (int f = 0; f < 108; ++f) bb += 2.f * b2[f] * fc1_w[f*512 + n];
    bias_eff[n] = bb;
  }
}

__global__ void POLAR_prep_fc2(const float* __restrict__ fc2_w,
                               unsigned short* __restrict__ fc2t) {
  int n = blockIdx.x;     // 0..191
  int k = threadIdx.x;    // 0..511
  float v = (n < 172) ? fc2_w[k*172 + n] : 0.f;
  fc2t[n*512 + k] = f2bf(v);
}

// ---------------- kernel A: row pipeline -> xbf (pre-swizzled, nt) ----------------
__global__ __launch_bounds__(512) void POLAR_rows(
    const float* __restrict__ emb, const int* __restrict__ idx,
    const float* __restrict__ W1, const float* __restrict__ b1,
    const float* __restrict__ x2, unsigned short* __restrict__ xbf)
{
  __shared__ __attribute__((aligned(16))) char rsm[RLDS_SZ];
  const int tid = threadIdx.x, blk = blockIdx.x;

  // gather: 8 threads/row, issue early
  const int p = tid >> 3, q = tid & 7;
  const size_t row = (size_t)blk * 64 + p;
  int key = idx[row];
  const float* ep = emb + (size_t)key * 8;
  f32x4 e0 = *(const f32x4*)ep;
  f32x4 e1 = *(const f32x4*)(ep + 4);

  // stage W1[432] + b1[108]
  float* wsl = (float*)(rsm + RLDS_W);
  for (int tt = tid; tt < 540; tt += 512)
    wsl[tt] = (tt < 432) ? W1[tt] : b1[tt - 432];
  __syncthreads();

  // PE MLP -> LDS cols 0..107 (swizzled, packed u32 pair stores)
  {
    unsigned sw = ((unsigned)(p >> 1) & 3u) << 4;
    char* xr = rsm + p * XROW_B;
    #pragma unroll
    for (int i2 = 0; i2 < 7; ++i2) {
      int e = q * 14 + 2 * i2;
      if (e < 108) {
        float wa0 = wsl[e],   wa1 = wsl[108+e], wa2 = wsl[216+e], wa3 = wsl[324+e], ba = wsl[432+e];
        float wb0 = wsl[e+1], wb1 = wsl[109+e], wb2 = wsl[217+e], wb3 = wsl[325+e], bb = wsl[433+e];
        float a = fmaxf(e0.x*wa0 + e0.y*wa1 + e0.z*wa2 + e0.w*wa3 + ba, 0.f)
                + fmaxf(e1.x*wa0 + e1.y*wa1 + e1.z*wa2 + e1.w*wa3 + ba, 0.f);
        float b = fmaxf(e0.x*wb0 + e0.y*wb1 + e0.z*wb2 + e0.w*wb3 + bb, 0.f)
                + fmaxf(e1.x*wb0 + e1.y*wb1 + e1.z*wb2 + e1.w*wb3 + bb, 0.f);
        unsigned pk = (unsigned)f2bf(a) | ((unsigned)f2bf(b) << 16);
        *(unsigned*)(xr + ((unsigned)(2 * e) ^ sw)) = pk;
      }
    }
  }

  // x2 -> LDS cols 108..279 (bf16, swizzled); zero pad 280..287
  {
    const f32x4* x2v = (const f32x4*)(x2 + (size_t)blk * 64 * 172);
    #pragma unroll 1
    for (int tt = tid; tt < 64 * 43; tt += 512) {
      int rr = tt / 43, c4 = tt - rr * 43;
      f32x4 v = x2v[tt];
      u16x4 s; s.x = f2bf(v.x); s.y = f2bf(v.y); s.z = f2bf(v.z); s.w = f2bf(v.w);
      unsigned sw = ((unsigned)(rr >> 1) & 3u) << 4;
      *(u16x4*)(rsm + rr * XROW_B + ((216u + 8u * (unsigned)c4) ^ sw)) = s;
    }
    if (tid < 64) {
      unsigned sw = ((unsigned)(tid >> 1) & 3u) << 4;
      f32x4 z = (f32x4){0.f, 0.f, 0.f, 0.f};
      *(f32x4*)(rsm + tid * XROW_B + (560u ^ sw)) = z;
    }
  }
  __syncthreads();

  // coalesced NT copy LDS -> xbf (verbatim bytes, swizzle preserved)
  {
    f32x4* dst = (f32x4*)((char*)xbf + (size_t)blk * 36864);
    const f32x4* src = (const f32x4*)rsm;
    #pragma unroll
    for (int k2 = 0; k2 < 4; ++k2)
      __builtin_nontemporal_store(src[tid + k2 * 512], &dst[tid + k2 * 512]);
    if (tid < 256)
      __builtin_nontemporal_store(src[tid + 2048], &dst[tid + 2048]);
  }
}

// ---------------- kernel B: fused GEMM1/GEMM2, quarter-interleaved ----------------
__global__ __launch_bounds__(512, 6) void POLAR_gemm(
    const unsigned short* __restrict__ xbf,
    const unsigned short* __restrict__ fc1t,
    const float* __restrict__ bias_eff,
    const unsigned short* __restrict__ fc2t,
    const float* __restrict__ fc2b,
    float* __restrict__ out)
{
  __shared__ __attribute__((aligned(16))) char smem[LDS_SZ];
  const int tid  = threadIdx.x;
  const int lane = tid & 63;
  const int w    = tid >> 6;      // 0..7
  const int blk  = blockIdx.x;
  const int l15  = lane & 15;
  const int l4   = lane >> 4;     // k-slot 0..3
  const int wm   = w >> 2;        // 0..1 : 32-row strip
  const int wn   = w & 3;         // 0..3 : col group

  // stage x tile [64][288] bf16 (content pre-swizzled -> linear LDS dest)
  {
    const char* xsrc = (const char*)xbf + (size_t)blk * 36864;
    #pragma unroll
    for (int c = w; c < 36; c += 8)
      g2l16(xsrc + c * 1024 + lane * 16, smem + c * 1024);
  }

  // wave-fixed addressing (imm offsets do the K-stepping)
  unsigned abase[2], hbase[2];
  #pragma unroll
  for (int i = 0; i < 2; ++i) {
    int row = wm * 32 + i * 16 + l15;
    unsigned sw = ((unsigned)(row >> 1) & 3u) << 4;
    abase[i] = (unsigned)(row * XROW_B) + (((unsigned)(l4 * 16)) ^ sw);
    hbase[i] = (unsigned)(HQ_OFF + row * HQROW_B) + (((unsigned)(l4 * 16)) ^ sw);
  }
  unsigned b1off[2];
  #pragma unroll
  for (int j = 0; j < 2; ++j)
    b1off[j] = (unsigned)((wn * 32 + j * 16 + l15) * 576 + l4 * 16);
  unsigned b2off[3];
  #pragma unroll
  for (int j = 0; j < 3; ++j)
    b2off[j] = (unsigned)((wn * 48 + j * 16 + l15) * 1024 + l4 * 16);

  f32x4 acc2[2][3];
  #pragma unroll
  for (int i = 0; i < 2; ++i)
    #pragma unroll
    for (int j = 0; j < 3; ++j)
      acc2[i][j] = (f32x4){0.f, 0.f, 0.f, 0.f};

  __syncthreads();   // x ready (g2l drained by barrier)

  #pragma unroll 1
  for (int q = 0; q < 4; ++q) {
    // ---- GEMM1 pass q: cols q*128 .. q*128+127 ----
    f32x4 acc[2][2];
    #pragma unroll
    for (int i = 0; i < 2; ++i)
      #pragma unroll
      for (int j = 0; j < 2; ++j)
        acc[i][j] = (f32x4){0.f, 0.f, 0.f, 0.f};

    const char* fbq = (const char*)fc1t + q * 73728;   // +q*128 rows of fc1t
    #pragma unroll 3
    for (int kt = 0; kt < 9; ++kt) {
      bf16x8 bv0 = *(const bf16x8*)(fbq + b1off[0] + kt * 64);
      bf16x8 bv1 = *(const bf16x8*)(fbq + b1off[1] + kt * 64);
      bf16x8 af0 = *(const bf16x8*)(smem + abase[0] + kt * 64);
      bf16x8 af1 = *(const bf16x8*)(smem + abase[1] + kt * 64);
      acc[0][0] = __builtin_amdgcn_mfma_f32_16x16x32_bf16(af0, bv0, acc[0][0], 0, 0, 0);
      acc[1][0] = __builtin_amdgcn_mfma_f32_16x16x32_bf16(af1, bv0, acc[1][0], 0, 0, 0);
      acc[0][1] = __builtin_amdgcn_mfma_f32_16x16x32_bf16(af0, bv1, acc[0][1], 0, 0, 0);
      acc[1][1] = __builtin_amdgcn_mfma_f32_16x16x32_bf16(af1, bv1, acc[1][1], 0, 0, 0);
    }
    __syncthreads();   // previous GEMM2 quarter's h reads complete

    // ---- epilogue: h quarter -> LDS (relu + bias, cvt_pk pack, swizzled) ----
    {
      const int odd = lane & 1;
      #pragma unroll
      for (int i = 0; i < 2; ++i) {
        #pragma unroll
        for (int j = 0; j < 2; ++j) {
          int ch = wn * 32 + j * 16 + l15;            // col within quarter
          float be = bias_eff[q * 128 + ch];
          float a0 = fmaxf(acc[i][j][0] + be, 0.f);
          float a1 = fmaxf(acc[i][j][1] + be, 0.f);
          float a2 = fmaxf(acc[i][j][2] + be, 0.f);
          float a3 = fmaxf(acc[i][j][3] + be, 0.f);
          float t0 = odd ? a0 : a2;
          float t1 = odd ? a1 : a3;
          float p0 = __shfl_xor(t0, 1);
          float p1 = __shfl_xor(t1, 1);
          unsigned w0 = cvtpk(odd ? p0 : a0, odd ? a2 : p0);
          unsigned w1 = cvtpk(odd ? p1 : a1, odd ? a3 : p1);
          int row0 = wm * 32 + i * 16 + l4 * 4 + (odd ? 2 : 0);
          int row1 = row0 + 1;
          unsigned cb = (unsigned)((ch & ~1) * 2);
          *(unsigned*)(smem + HQ_OFF + row0 * HQROW_B
                       + (cb ^ ((((unsigned)row0 >> 1) & 3u) << 4))) = w0;
          *(unsigned*)(smem + HQ_OFF + row1 * HQROW_B
                       + (cb ^ ((((unsigned)row1 >> 1) & 3u) << 4))) = w1;
        }
      }
    }
    __syncthreads();   // h quarter ready

    // ---- GEMM2 quarter q: k = q*128 .. q*128+127 (acc2 accumulates) ----
    const char* fb2q = (const char*)fc2t + q * 256;
    #pragma unroll
    for (int ks = 0; ks < 4; ++ks) {
      bf16x8 b20 = *(const bf16x8*)(fb2q + b2off[0] + ks * 64);
      bf16x8 b21 = *(const bf16x8*)(fb2q + b2off[1] + ks * 64);
      bf16x8 b22 = *(const bf16x8*)(fb2q + b2off[2] + ks * 64);
      bf16x8 a20 = *(const bf16x8*)(smem + hbase[0] + ks * 64);
      bf16x8 a21 = *(const bf16x8*)(smem + hbase[1] + ks * 64);
      acc2[0][0] = __builtin_amdgcn_mfma_f32_16x16x32_bf16(a20, b20, acc2[0][0], 0, 0, 0);
      acc2[1][0] = __builtin_amdgcn_mfma_f32_16x16x32_bf16(a21, b20, acc2[1][0], 0, 0, 0);
      acc2[0][1] = __builtin_amdgcn_mfma_f32_16x16x32_bf16(a20, b21, acc2[0][1], 0, 0, 0);
      acc2[1][1] = __builtin_amdgcn_mfma_f32_16x16x32_bf16(a21, b21, acc2[1][1], 0, 0, 0);
      acc2[0][2] = __builtin_amdgcn_mfma_f32_16x16x32_bf16(a20, b22, acc2[0][2], 0, 0, 0);
      acc2[1][2] = __builtin_amdgcn_mfma_f32_16x16x32_bf16(a21, b22, acc2[1][2], 0, 0, 0);
    }
  }

  // ---- epilogue 2: out = acc2 + fc2_b (mask cols >= 172) ----
  const size_t orow0 = (size_t)blk * 64;
  #pragma unroll
  for (int j = 0; j < 3; ++j) {
    int col = wn * 48 + j * 16 + l15;
    if (col < 172) {
      float bias = fc2b[col];
      #pragma unroll
      for (int i = 0; i < 2; ++i) {
        #pragma unroll
        for (int r2 = 0; r2 < 4; ++r2) {
          int row = wm * 32 + i * 16 + l4 * 4 + r2;
          out[(orow0 + row) * 172 + col] = acc2[i][j][r2] + bias;
        }
      }
    }
  }
}

extern "C" void kernel_launch(void* const* d_in, const int* in_sizes, int n_in,
                              void* d_out, int out_size, void* d_ws, size_t ws_size,
                              hipStream_t stream) {
  (void)in_sizes; (void)n_in; (void)out_size; (void)ws_size;
  const float* emb   = (const float*)d_in[0];
  const int*   idx   = (const int*)d_in[1];
  const float* W1    = (const float*)d_in[2];
  const float* b1    = (const float*)d_in[3];
  const float* W2    = (const float*)d_in[4];
  const float* b2    = (const float*)d_in[5];
  const float* x2    = (const float*)d_in[6];
  const float* fc1_w = (const float*)d_in[7];
  const float* fc1_b = (const float*)d_in[8];
  const float* fc2_w = (const float*)d_in[9];
  const float* fc2_b = (const float*)d_in[10];
  float* out = (float*)d_out;
  char* ws = (char*)d_ws;
  unsigned short* fc1t = (unsigned short*)(ws + WS_FC1T);
  unsigned short* fc2t = (unsigned short*)(ws + WS_FC2T);
  float* bias_eff = (float*)(ws + WS_BIAS);
  unsigned short* xbf  = (unsigned short*)(ws + WS_XBF);

  POLAR_prep_fc1<<<512, 288, 0, stream>>>(W2, fc1_w, fc1_b, b2, fc1t, bias_eff);
  POLAR_prep_fc2<<<192, 512, 0, stream>>>(fc2_w, fc2t);
  POLAR_rows<<<4096, 512, 0, stream>>>(emb, idx, W1, b1, x2, xbf);
  POLAR_gemm<<<4096, 512, 0, stream>>>(xbf, fc1t, bias_eff, fc2t, fc2_b, out);
}

// Round 9
// 357.083 us; speedup vs baseline: 1.3946x; 1.3946x over previous
//
#include <hip/hip_runtime.h>
#include <stdint.h>

typedef __bf16 bf16x8 __attribute__((ext_vector_type(8)));
typedef float  f32x4  __attribute__((ext_vector_type(4)));
typedef unsigned short u16x4 __attribute__((ext_vector_type(4)));

// ---- geometry (R4 structure + nt-stream isolation + XCD swizzle) ----
// 64 rows/block, 512 threads (8 waves), 4096 blocks -> 2 blocks/CU resident.
// GEMM1: [64 x 288] x [288 x 512], wave grid 1M x 8N, acc[4][4], 9 kt of 32
// GEMM2: [64 x 512] x [512 x 192], wave grid 2M x 4N, acc2[2][3], 8 kt of 64
// B operands direct from global + 1-deep reg prefetch. Streams (x2 in, out)
// use nontemporal hints so the 480 KB weight panels stay L2-resident.
#define XROW_B 576      // x LDS row stride bytes (288 bf16)
#define HROW_B 1024     // h LDS row stride bytes (512 bf16)
#define LDS_SZ 65536    // h [64][512] bf16; x [64][288] + Wstage overlap
#define WSTG   40960    // f32 W1[432]+b1[108] staged; dead region during PE

// workspace offsets (bytes)
#define WS_FC1T   0         // bf16 [512][288]  (fc1_eff transposed, K-padded)
#define WS_FC2T   294912    // bf16 [192][512]  (fc2_w transposed, N-padded)
#define WS_BIAS   491520    // f32  [512]       (folded bias)

__device__ __forceinline__ unsigned short f2bf(float f) {
  union { float f; unsigned u; } c; c.f = f;
  unsigned u = c.u;
  u += 0x7FFFu + ((u >> 16) & 1u);   // RTNE
  return (unsigned short)(u >> 16);
}

// ---------------- prep: fold W2 into fc1_w, transpose + bf16 ----------------
__global__ void POLAR_prep_fc1(const float* __restrict__ W2,
                               const float* __restrict__ fc1_w,
                               const float* __restrict__ fc1_b,
                               const float* __restrict__ b2,
                               unsigned short* __restrict__ fc1t,
                               float* __restrict__ bias_eff) {
  int n = blockIdx.x;      // 0..511
  int k = threadIdx.x;     // 0..287
  float v = 0.f;
  if (k < 108) {           // folded: sum_f W2[k,f] * fc1_w[f,n]
    for (int f = 0; f < 108; ++f) v += W2[k*108 + f] * fc1_w[f*512 + n];
  } else if (k < 280) {    // x2 part of fc1_w
    v = fc1_w[k*512 + n];
  }
  fc1t[n*288 + k] = f2bf(v);
  if (k == 0) {
    float bb = fc1_b[n];
    for (int f = 0; f < 108; ++f) bb += 2.f * b2[f] * fc1_w[f*512 + n];
    bias_eff[n] = bb;
  }
}

__global__ void POLAR_prep_fc2(const float* __restrict__ fc2_w,
                               unsigned short* __restrict__ fc2t) {
  int n = blockIdx.x;     // 0..191
  int k = threadIdx.x;    // 0..511
  float v = (n < 172) ? fc2_w[k*172 + n] : 0.f;
  fc2t[n*512 + k] = f2bf(v);
}

// ---------------- fused main kernel ----------------
__global__ __launch_bounds__(512, 4) void POLAR_fused(
    const float* __restrict__ emb, const int* __restrict__ idx,
    const float* __restrict__ W1, const float* __restrict__ b1,
    const float* __restrict__ x2,
    const unsigned short* __restrict__ fc1t,   // bf16 [512][288]
    const float* __restrict__ bias_eff,        // [512]
    const unsigned short* __restrict__ fc2t,   // bf16 [192][512]
    const float* __restrict__ fc2b,            // [172]
    float* __restrict__ out)
{
  __shared__ __attribute__((aligned(16))) char smem[LDS_SZ];
  const int tid  = threadIdx.x;
  const int lane = tid & 63;
  const int w    = tid >> 6;      // 0..7
  // bijective XCD-chunk swizzle: 4096 blocks = 8 XCDs x 512 contiguous
  const int blk  = ((blockIdx.x & 7) << 9) | (blockIdx.x >> 3);
  const int l15  = lane & 15;
  const int l4   = lane >> 4;     // k-slot 0..3

  const char* fb1 = (const char*)fc1t;
  const char* fb2 = (const char*)fc2t;

  // ---- B1 kt=0 prefetch (completes under PE phase) ----
  unsigned boff1[4];
  bf16x8 bva[4], bvb[4];
  #pragma unroll
  for (int j = 0; j < 4; ++j) {
    boff1[j] = (unsigned)((w * 64 + j * 16 + l15) * 576 + l4 * 16);
    bva[j] = *(const bf16x8*)(fb1 + boff1[j]);            // kt = 0
  }

  // ---- gather (issue early; latency overlaps W-stage) ----
  const int r  = tid >> 3;        // 0..63 (8 threads/row)
  const int li = tid & 7;
  int key = idx[(size_t)blk * 64 + r];
  const float* ep = emb + (size_t)key * 8;
  f32x4 e0 = *(const f32x4*)ep;
  f32x4 e1 = *(const f32x4*)(ep + 4);

  // ---- stage W1[432]+b1[108] into LDS (region dead during PE) ----
  {
    float* wsl = (float*)(smem + WSTG);
    if (tid < 432) wsl[tid] = W1[tid];
    else if (tid < 540) wsl[tid] = b1[tid - 432];
    int t2 = tid + 512;
    if (t2 < 540) wsl[t2] = b1[t2 - 432];
  }
  __syncthreads();   // (0) Wstage ready

  // ---- PE phase: hsum -> x cols 0..107 (bf16, slot-swizzled) ----
  {
    const float* Ws = (const float*)(smem + WSTG);
    unsigned sw = ((unsigned)(r >> 1) & 3u) << 4;
    for (int e = li; e < 108; e += 8) {
      float w0 = Ws[e], w1v = Ws[108 + e], w2v = Ws[216 + e], w3v = Ws[324 + e];
      float bb = Ws[432 + e];
      float a0 = fmaxf(e0.x*w0 + e0.y*w1v + e0.z*w2v + e0.w*w3v + bb, 0.f);
      float a1 = fmaxf(e1.x*w0 + e1.y*w1v + e1.z*w2v + e1.w*w3v + bb, 0.f);
      *(unsigned short*)(smem + r * XROW_B + ((unsigned)(2*e) ^ sw)) = f2bf(a0 + a1);
    }
  }

  // ---- x2 -> x cols 108..279 (bf16, NT loads), zero pad 280..287 ----
  {
    const f32x4* x2v = (const f32x4*)(x2 + (size_t)blk * 64 * 172);
    #pragma unroll 1
    for (int t = tid; t < 64 * 43; t += 512) {
      int rr = t / 43, c4 = t - rr * 43;
      f32x4 v = __builtin_nontemporal_load(&x2v[t]);
      u16x4 s; s.x = f2bf(v.x); s.y = f2bf(v.y); s.z = f2bf(v.z); s.w = f2bf(v.w);
      unsigned be = 216u + 8u * (unsigned)c4;
      unsigned sw = ((unsigned)(rr >> 1) & 3u) << 4;
      *(u16x4*)(smem + rr * XROW_B + (be ^ sw)) = s;
    }
    if (tid < 64) {
      unsigned sw = ((unsigned)(tid >> 1) & 3u) << 4;
      union { long2 l; } z; z.l.x = 0; z.l.y = 0;
      *(long2*)(smem + tid * XROW_B + (560u ^ sw)) = z.l;
    }
  }
  __syncthreads();   // (1) x ready

  // ---- GEMM1: wave grid 1M x 8N (wn = w); B from global, reg dbuf ----
  f32x4 acc[4][4];
  #pragma unroll
  for (int i = 0; i < 4; ++i)
    #pragma unroll
    for (int j = 0; j < 4; ++j)
      acc[i][j] = (f32x4){0.f, 0.f, 0.f, 0.f};

  unsigned abase[4];
  #pragma unroll
  for (int i = 0; i < 4; ++i) {
    int row = i * 16 + l15;
    abase[i] = (unsigned)(row * XROW_B)
             + (((unsigned)(l4 * 16)) ^ ((((unsigned)row >> 1) & 3u) << 4));
  }

  bf16x8 af[4];
  #pragma unroll 1
  for (int kt = 0; kt < 8; kt += 2) {
    #pragma unroll
    for (int j = 0; j < 4; ++j)
      bvb[j] = *(const bf16x8*)(fb1 + boff1[j] + (kt + 1) * 64);
    #pragma unroll
    for (int i = 0; i < 4; ++i)
      af[i] = *(const bf16x8*)(smem + abase[i] + kt * 64);
    #pragma unroll
    for (int i = 0; i < 4; ++i)
      #pragma unroll
      for (int j = 0; j < 4; ++j)
        acc[i][j] = __builtin_amdgcn_mfma_f32_16x16x32_bf16(af[i], bva[j], acc[i][j], 0, 0, 0);
    #pragma unroll
    for (int j = 0; j < 4; ++j)
      bva[j] = *(const bf16x8*)(fb1 + boff1[j] + (kt + 2) * 64);
    #pragma unroll
    for (int i = 0; i < 4; ++i)
      af[i] = *(const bf16x8*)(smem + abase[i] + (kt + 1) * 64);
    #pragma unroll
    for (int i = 0; i < 4; ++i)
      #pragma unroll
      for (int j = 0; j < 4; ++j)
        acc[i][j] = __builtin_amdgcn_mfma_f32_16x16x32_bf16(af[i], bvb[j], acc[i][j], 0, 0, 0);
  }
  {  // tail kt = 8 (uses bva prefetched in last iteration)
    #pragma unroll
    for (int i = 0; i < 4; ++i)
      af[i] = *(const bf16x8*)(smem + abase[i] + 8 * 64);
    #pragma unroll
    for (int i = 0; i < 4; ++i)
      #pragma unroll
      for (int j = 0; j < 4; ++j)
        acc[i][j] = __builtin_amdgcn_mfma_f32_16x16x32_bf16(af[i], bva[j], acc[i][j], 0, 0, 0);
  }
  __syncthreads();   // (2) x reads done; region may be overwritten by h

  // ---- B2 kt=0 prefetch (completes under epilogue 1) ----
  const int wm4 = w >> 2;         // 0..1 : rows wm4*32, 2 frags
  const int wn4 = w & 3;          // 0..3 : cols wn4*48, 3 frags
  unsigned boff2[3];
  bf16x8 b2a[3][2], b2b[3][2];
  #pragma unroll
  for (int j = 0; j < 3; ++j) {
    boff2[j] = (unsigned)((wn4 * 48 + j * 16 + l15) * 1024 + l4 * 16);
    #pragma unroll
    for (int s = 0; s < 2; ++s)
      b2a[j][s] = *(const bf16x8*)(fb2 + boff2[j] + s * 64);   // kt = 0
  }

  // ---- epilogue 1: h = relu(acc + bias_eff) -> LDS, swizzled; DPP pack ----
  {
    const int odd = lane & 1;
    #pragma unroll
    for (int i = 0; i < 4; ++i) {
      #pragma unroll
      for (int j = 0; j < 4; ++j) {
        int col0 = w * 64 + j * 16 + l15;
        float be = bias_eff[col0];
        float a0 = fmaxf(acc[i][j][0] + be, 0.f);
        float a1 = fmaxf(acc[i][j][1] + be, 0.f);
        float a2 = fmaxf(acc[i][j][2] + be, 0.f);
        float a3 = fmaxf(acc[i][j][3] + be, 0.f);
        float t0 = odd ? a0 : a2;
        float t1 = odd ? a1 : a3;
        float p0 = __shfl_xor(t0, 1);
        float p1 = __shfl_xor(t1, 1);
        unsigned w0 = odd ? ((unsigned)f2bf(p0) | ((unsigned)f2bf(a2) << 16))
                          : ((unsigned)f2bf(a0) | ((unsigned)f2bf(p0) << 16));
        unsigned w1 = odd ? ((unsigned)f2bf(p1) | ((unsigned)f2bf(a3) << 16))
                          : ((unsigned)f2bf(a1) | ((unsigned)f2bf(p1) << 16));
        int row0 = i * 16 + l4 * 4 + (odd ? 2 : 0);
        int row1 = row0 + 1;
        unsigned cb = (unsigned)((col0 & ~1) * 2);
        *(unsigned*)(smem + row0 * HROW_B + (cb ^ (((unsigned)row0 & 7u) << 4))) = w0;
        *(unsigned*)(smem + row1 * HROW_B + (cb ^ (((unsigned)row1 & 7u) << 4))) = w1;
      }
    }
  }
  __syncthreads();   // (3) h ready

  // ---- GEMM2: wave grid 2M x 4N; BK=128/iter; B prefetched 1 kt deep ----
  f32x4 acc2[2][3];
  #pragma unroll
  for (int i = 0; i < 2; ++i)
    #pragma unroll
    for (int j = 0; j < 3; ++j)
      acc2[i][j] = (f32x4){0.f, 0.f, 0.f, 0.f};

  unsigned h0base[2], swr2[2];
  #pragma unroll
  for (int i = 0; i < 2; ++i) {
    int row = wm4 * 32 + i * 16 + l15;
    h0base[i] = (unsigned)(row * HROW_B);
    swr2[i] = (((unsigned)row & 7u) << 4);
  }

  bf16x8 a2[2][2];
  #pragma unroll 1
  for (int kt = 0; kt < 8; kt += 2) {
    #pragma unroll
    for (int j = 0; j < 3; ++j)
      #pragma unroll
      for (int s = 0; s < 2; ++s)
        b2b[j][s] = *(const bf16x8*)(fb2 + boff2[j] + (kt + 1) * 128 + s * 64);
    #pragma unroll
    for (int i = 0; i < 2; ++i)
      #pragma unroll
      for (int s = 0; s < 2; ++s)
        a2[i][s] = *(const bf16x8*)(smem + h0base[i]
                     + (((unsigned)(kt * 128 + s * 64 + l4 * 16)) ^ swr2[i]));
    #pragma unroll
    for (int s = 0; s < 2; ++s)
      #pragma unroll
      for (int i = 0; i < 2; ++i)
        #pragma unroll
        for (int j = 0; j < 3; ++j)
          acc2[i][j] = __builtin_amdgcn_mfma_f32_16x16x32_bf16(a2[i][s], b2a[j][s], acc2[i][j], 0, 0, 0);
    if (kt < 6) {
      #pragma unroll
      for (int j = 0; j < 3; ++j)
        #pragma unroll
        for (int s = 0; s < 2; ++s)
          b2a[j][s] = *(const bf16x8*)(fb2 + boff2[j] + (kt + 2) * 128 + s * 64);
    }
    #pragma unroll
    for (int i = 0; i < 2; ++i)
      #pragma unroll
      for (int s = 0; s < 2; ++s)
        a2[i][s] = *(const bf16x8*)(smem + h0base[i]
                     + (((unsigned)((kt + 1) * 128 + s * 64 + l4 * 16)) ^ swr2[i]));
    #pragma unroll
    for (int s = 0; s < 2; ++s)
      #pragma unroll
      for (int i = 0; i < 2; ++i)
        #pragma unroll
        for (int j = 0; j < 3; ++j)
          acc2[i][j] = __builtin_amdgcn_mfma_f32_16x16x32_bf16(a2[i][s], b2b[j][s], acc2[i][j], 0, 0, 0);
  }

  // ---- epilogue 2: out = acc2 + fc2_b (mask cols >= 172), NT stores ----
  const size_t orow0 = (size_t)blk * 64;
  #pragma unroll
  for (int j = 0; j < 3; ++j) {
    int col = wn4 * 48 + j * 16 + l15;
    if (col < 172) {
      float bias = fc2b[col];
      #pragma unroll
      for (int i = 0; i < 2; ++i) {
        #pragma unroll
        for (int r2 = 0; r2 < 4; ++r2) {
          int row = wm4 * 32 + i * 16 + l4 * 4 + r2;
          __builtin_nontemporal_store(acc2[i][j][r2] + bias,
                                      &out[(orow0 + row) * 172 + col]);
        }
      }
    }
  }
}

extern "C" void kernel_launch(void* const* d_in, const int* in_sizes, int n_in,
                              void* d_out, int out_size, void* d_ws, size_t ws_size,
                              hipStream_t stream) {
  (void)in_sizes; (void)n_in; (void)out_size; (void)ws_size;
  const float* emb   = (const float*)d_in[0];
  const int*   idx   = (const int*)d_in[1];
  const float* W1    = (const float*)d_in[2];
  const float* b1    = (const float*)d_in[3];
  const float* W2    = (const float*)d_in[4];
  const float* b2    = (const float*)d_in[5];
  const float* x2    = (const float*)d_in[6];
  const float* fc1_w = (const float*)d_in[7];
  const float* fc1_b = (const float*)d_in[8];
  const float* fc2_w = (const float*)d_in[9];
  const float* fc2_b = (const float*)d_in[10];
  float* out = (float*)d_out;
  char* ws = (char*)d_ws;
  unsigned short* fc1t = (unsigned short*)(ws + WS_FC1T);
  unsigned short* fc2t = (unsigned short*)(ws + WS_FC2T);
  float* bias_eff = (float*)(ws + WS_BIAS);

  POLAR_prep_fc1<<<512, 288, 0, stream>>>(W2, fc1_w, fc1_b, b2, fc1t, bias_eff);
  POLAR_prep_fc2<<<192, 512, 0, stream>>>(fc2_w, fc2t);
  POLAR_fused<<<4096, 512, 0, stream>>>(emb, idx, W1, b1, x2, fc1t, bias_eff,
                                        fc2t, fc2_b, out);
}